// Round 14
// baseline (279.847 us; speedup 1.0000x reference)
//
#include <hip/hip_runtime.h>
#include <hip/hip_bf16.h>
#include <hip/hip_fp16.h>

#define N_NODES 50000
#define N_EDGES 640000
#define N_GRAPHS 500
#define D 128
#define CAP 64   // neighbor slots per node; max degree here ~35 (Poisson 12.8)

#define PREP_X_BLOCKS (N_NODES * D / 8 / 256) // 3125 (exact)
#define PREP_E_BLOCKS (N_EDGES / 256)         // 2500 (exact), 1 edge/thread
#define PREP_W_BLOCKS (6 * D * D / 256)       // 384 (exact)

typedef _Float16 h8_t __attribute__((ext_vector_type(8)));   // 8 fp16 = 4 VGPRs
typedef __attribute__((ext_vector_type(4))) float f4_t;

// ---------------------------------------------------------------------------
// prep: (a) binned-CSR fill (1 edge/thread; atomic-rate-bound),
//       (b) x fp32->fp16, (c) W (L,K,N) fp32 -> fp16 transposed (L,N,K).
// ---------------------------------------------------------------------------
__global__ __launch_bounds__(256) void gin_prep_kernel(
    const float* __restrict__ x, _Float16* __restrict__ xh,
    const int* __restrict__ src, const int* __restrict__ dst,
    int* __restrict__ cnt, int* __restrict__ slots,
    const float* __restrict__ W1, const float* __restrict__ W2,
    _Float16* __restrict__ Wt1, _Float16* __restrict__ Wt2)
{
    const int b = blockIdx.x, t = threadIdx.x;
    if (b < PREP_E_BLOCKS) {
        int e = b * 256 + t;                       // one edge per thread
        int s = src[e];
        int d = dst[e];
        int sl = atomicAdd(&cnt[d], 1);
        if (sl < CAP) slots[(d << 6) + sl] = s;
    } else if (b < PREP_E_BLOCKS + PREP_X_BLOCKS) {
        int i = (b - PREP_E_BLOCKS) * 256 + t;     // h8-unit index
        const float4* p = (const float4*)x;
        float4 v0 = p[2 * i], v1 = p[2 * i + 1];
        h8_t o;
        o[0] = (_Float16)v0.x; o[1] = (_Float16)v0.y;
        o[2] = (_Float16)v0.z; o[3] = (_Float16)v0.w;
        o[4] = (_Float16)v1.x; o[5] = (_Float16)v1.y;
        o[6] = (_Float16)v1.z; o[7] = (_Float16)v1.w;
        ((h8_t*)xh)[i] = o;
    } else {
        int idx = (b - PREP_E_BLOCKS - PREP_X_BLOCKS) * 256 + t;
        int m = idx >> 14;
        int r = idx & 16383;
        int n = r >> 7, k = r & 127;
        const float* srcw = (m < 3) ? (W1 + ((long)m << 14)) : (W2 + ((long)(m - 3) << 14));
        _Float16* dstw = (m < 3) ? (Wt1 + ((long)m << 14)) : (Wt2 + ((long)(m - 3) << 14));
        dstw[(n << 7) | k] = (_Float16)srcw[(k << 7) | n];   // Wt[n][k] = W[k][n]
    }
}

// ---------------------------------------------------------------------------
// FUSED LAYER v7: out = relu(BN(relu((x_self + sum_n x) @ W1 + b1) @ W2 + b2))
// Block = 256 thr (4 waves) owns 32 nodes; grid 1563; launch_bounds(256,6)
// -> ~85 VGPR cap (NO spill — r13's 2-window pipeline spilled at VGPR=32,
// WRITE_SIZE +6.25MB) and 24 waves/CU.
//  phase G (HALF-WAVE NODE PAIR): lanes 0-31 = node A, lanes 32-63 = node B;
//   each lane covers 8B (uint2 = 4 fp16) of a 256B row. ONE load instruction
//   fetches TWO rows -> a 16-deep window = 32 rows in flight per wave with
//   only 32 data VGPRs, one vmcnt drain per TWO nodes, half the issue slots.
//   Slot indices: single 32-slot preload + __shfl(pre,i,32) per-half
//   broadcast (no extra memory ops). Clamped j=0 for i>=cnt; masked adds.
//   4 independent f64 accumulator chains per lane (2x the f64 ILP of r12).
//   Residual deg>16 via shfl chunks (16..31) and direct loads (32..cnt).
//   DOUBLE accumulation: fp16 vals are multiples of 2^-24, |v|<2^6, deg<2^6
//   -> sums EXACT -> bit-identical for ANY slot order (atomics vary per call).
//  stage 1: a_s @ W1 (MFMA, 4 waves x 2 col tiles), h=relu(+b1) back into a_s.
//  stage 2: out = relu(BN(a_s @ W2 + b2)) -> global.
// in/out must differ (caller ping-pongs).
// ---------------------------------------------------------------------------
constexpr int ASTR = 136;   // fp16 elems/row in LDS: +8 pad (272B, 16B-aligned)

__device__ __forceinline__ float2 unpack_h2(unsigned v) {
    __half2 h = __builtin_bit_cast(__half2, v);
    return __half22float2(h);
}

__device__ __forceinline__ void acc4(double& a0, double& a1, double& a2, double& a3,
                                     unsigned mx, unsigned my) {
    float2 g0 = unpack_h2(mx);
    float2 g1 = unpack_h2(my);
    a0 += (double)g0.x; a1 += (double)g0.y;
    a2 += (double)g1.x; a3 += (double)g1.y;
}

__global__ __launch_bounds__(256, 6) void gin_layer_kernel(
    const _Float16* __restrict__ x,
    const int* __restrict__ cnt, const int* __restrict__ slots,
    const _Float16* __restrict__ Wt1, const float* __restrict__ b1,
    const _Float16* __restrict__ Wt2, const float* __restrict__ b2,
    const float* __restrict__ bn_scale, const float* __restrict__ bn_bias,
    const float* __restrict__ bn_mean, const float* __restrict__ bn_var,
    _Float16* __restrict__ out, int N)
{
    __shared__ __align__(16) _Float16 a_s[32 * ASTR];
    __shared__ float ep_a[D], ep_b[D], b1_s[D];

    const int tid = threadIdx.x;
    if (tid < D) {
        float sc = bn_scale[tid] * rsqrtf(bn_var[tid] + 1e-5f);
        ep_a[tid] = sc;
        ep_b[tid] = (b2[tid] - bn_mean[tid]) * sc + bn_bias[tid];
        b1_s[tid] = b1[tid];
    }

    const int row0 = blockIdx.x * 32;
    const int lane = tid & 63;
    const int wave = tid >> 6;            // 0..3
    const int s    = lane & 31;           // uint2 index within row (8B each)
    const uint2* __restrict__ xw2 = (const uint2*)x;   // row = 32 uint2

    // ---- phase G: half-wave node-pair gather ----
    #pragma unroll 1
    for (int pass = 0; pass < 4; ++pass) {
        const int nl = pass * 8 + wave * 2 + (lane >> 5);   // per-lane node 0..31
        const int node = row0 + nl;
        const int node_c = min(node, N - 1);                // clamp (pad nodes: garbage, finite)
        const int cn = cnt[node_c];                         // broadcast within half
        const long sb = (long)node_c << 6;

        // preload this half's slots 0..31 (lane s -> slot s); poison beyond cnt
        // is clamped to j=0 before use.
        const int pre = slots[sb + s];

        // self row (2 segments per instruction: half A row + half B row)
        uint2 sv = xw2[(long)node_c * 32 + s];

        // 16-deep window: 32 rows in flight per wave
        uint2 v[16];
        #pragma unroll
        for (int i = 0; i < 16; ++i) {
            int ji = __shfl(pre, i, 32);                    // per-half broadcast
            int j = (i < cn) ? ji : 0;                      // clamp poison/invalid
            v[i] = xw2[(long)j * 32 + s];
        }

        double a0, a1, a2, a3;
        {
            float2 g0 = unpack_h2(sv.x), g1 = unpack_h2(sv.y);
            a0 = (double)g0.x; a1 = (double)g0.y;
            a2 = (double)g1.x; a3 = (double)g1.y;
        }
        #pragma unroll
        for (int i = 0; i < 16; ++i) {
            unsigned mx = (i < cn) ? v[i].x : 0u;
            unsigned my = (i < cn) ? v[i].y : 0u;
            acc4(a0, a1, a2, a3, mx, my);
        }

        // residual 16..31 via shfl chunks (uniform k -> uniform branch)
        #pragma unroll
        for (int k0 = 16; k0 < 32; k0 += 8) {
            if (__any(cn > k0)) {
                uint2 vv[8];
                #pragma unroll
                for (int i = 0; i < 8; ++i) {
                    int kk = k0 + i;
                    int ji = __shfl(pre, kk, 32);
                    int j = (kk < cn) ? ji : 0;
                    vv[i] = xw2[(long)j * 32 + s];
                }
                #pragma unroll
                for (int i = 0; i < 8; ++i) {
                    unsigned mx = (k0 + i < cn) ? vv[i].x : 0u;
                    unsigned my = (k0 + i < cn) ? vv[i].y : 0u;
                    acc4(a0, a1, a2, a3, mx, my);
                }
            }
        }
        // ultra-rare deg>32: direct slot loads
        #pragma unroll 1
        for (int k0 = 32; __any(cn > k0); k0 += 8) {
            uint2 vv[8];
            #pragma unroll
            for (int i = 0; i < 8; ++i) {
                int kk = k0 + i;
                int jv = slots[sb + min(kk, CAP - 1)];
                int j = (kk < cn) ? jv : 0;
                vv[i] = xw2[(long)j * 32 + s];
            }
            #pragma unroll
            for (int i = 0; i < 8; ++i) {
                unsigned mx = (k0 + i < cn) ? vv[i].x : 0u;
                unsigned my = (k0 + i < cn) ? vv[i].y : 0u;
                acc4(a0, a1, a2, a3, mx, my);
            }
        }

        // pack 4 channels -> uint2, store (2 LDS rows per wave instruction)
        _Float16 h0 = (_Float16)(float)a0, h1 = (_Float16)(float)a1;
        _Float16 h2 = (_Float16)(float)a2, h3 = (_Float16)(float)a3;
        uint2 pk;
        pk.x = (unsigned)__builtin_bit_cast(unsigned short, h0) |
               ((unsigned)__builtin_bit_cast(unsigned short, h1) << 16);
        pk.y = (unsigned)__builtin_bit_cast(unsigned short, h2) |
               ((unsigned)__builtin_bit_cast(unsigned short, h3) << 16);
        ((uint2*)(a_s + (long)nl * ASTR))[s] = pk;
    }
    __syncthreads();

    // ---- stage 1: a_s @ W1 ----  (wave w -> col tiles w*16 and w*16+64)
    const int m16 = lane & 15;
    const int kq  = lane >> 4;
    const int n0  = wave * 16;

    f4_t a1m[2][2];
    #pragma unroll
    for (int r = 0; r < 2; ++r)
        #pragma unroll
        for (int cc = 0; cc < 2; ++cc) a1m[r][cc] = (f4_t){0.f, 0.f, 0.f, 0.f};

    #pragma unroll
    for (int kc = 0; kc < 4; ++kc) {
        const int k0 = kc * 32 + kq * 8;
        h8_t af0 = *(const h8_t*)(a_s + m16 * ASTR + k0);
        h8_t af1 = *(const h8_t*)(a_s + (16 + m16) * ASTR + k0);
        h8_t bf0 = *(const h8_t*)(Wt1 + (long)(n0 + m16) * D + k0);
        h8_t bf1 = *(const h8_t*)(Wt1 + (long)(n0 + 64 + m16) * D + k0);
        a1m[0][0] = __builtin_amdgcn_mfma_f32_16x16x32_f16(af0, bf0, a1m[0][0], 0, 0, 0);
        a1m[1][0] = __builtin_amdgcn_mfma_f32_16x16x32_f16(af1, bf0, a1m[1][0], 0, 0, 0);
        a1m[0][1] = __builtin_amdgcn_mfma_f32_16x16x32_f16(af0, bf1, a1m[0][1], 0, 0, 0);
        a1m[1][1] = __builtin_amdgcn_mfma_f32_16x16x32_f16(af1, bf1, a1m[1][1], 0, 0, 0);
    }
    __syncthreads();   // all a_s reads done -> safe to overwrite

    // h = relu(a1m + b1) back into a_s  (C/D: col=m16, row=kq*4+g)
    #pragma unroll
    for (int cc = 0; cc < 2; ++cc) {
        const int coln = n0 + cc * 64 + m16;
        const float bb = b1_s[coln];
        #pragma unroll
        for (int r = 0; r < 2; ++r)
            #pragma unroll
            for (int g = 0; g < 4; ++g) {
                float vv = fmaxf(a1m[r][cc][g] + bb, 0.f);
                a_s[(r * 16 + kq * 4 + g) * ASTR + coln] = (_Float16)vv;
            }
    }
    __syncthreads();

    // ---- stage 2: out = relu(BN(a_s @ W2 + b2)) ----
    f4_t a2m[2][2];
    #pragma unroll
    for (int r = 0; r < 2; ++r)
        #pragma unroll
        for (int cc = 0; cc < 2; ++cc) a2m[r][cc] = (f4_t){0.f, 0.f, 0.f, 0.f};

    #pragma unroll
    for (int kc = 0; kc < 4; ++kc) {
        const int k0 = kc * 32 + kq * 8;
        h8_t af0 = *(const h8_t*)(a_s + m16 * ASTR + k0);
        h8_t af1 = *(const h8_t*)(a_s + (16 + m16) * ASTR + k0);
        h8_t bf0 = *(const h8_t*)(Wt2 + (long)(n0 + m16) * D + k0);
        h8_t bf1 = *(const h8_t*)(Wt2 + (long)(n0 + 64 + m16) * D + k0);
        a2m[0][0] = __builtin_amdgcn_mfma_f32_16x16x32_f16(af0, bf0, a2m[0][0], 0, 0, 0);
        a2m[1][0] = __builtin_amdgcn_mfma_f32_16x16x32_f16(af1, bf0, a2m[1][0], 0, 0, 0);
        a2m[0][1] = __builtin_amdgcn_mfma_f32_16x16x32_f16(af0, bf1, a2m[0][1], 0, 0, 0);
        a2m[1][1] = __builtin_amdgcn_mfma_f32_16x16x32_f16(af1, bf1, a2m[1][1], 0, 0, 0);
    }
    #pragma unroll
    for (int cc = 0; cc < 2; ++cc) {
        const int coln = n0 + cc * 64 + m16;
        const float ea = ep_a[coln], eb = ep_b[coln];
        #pragma unroll
        for (int r = 0; r < 2; ++r) {
            const int rb = row0 + r * 16 + kq * 4;
            #pragma unroll
            for (int g = 0; g < 4; ++g) {
                const int grow = rb + g;
                if (grow < N) {
                    float vv = fmaxf(fmaf(a2m[r][cc][g], ea, eb), 0.f);
                    out[(long)grow * D + coln] = (_Float16)vv;
                }
            }
        }
    }
}

// ---------------------------------------------------------------------------
// fused pool+head: one block (128 thr) per graph. batch sorted -> binary
// search; fixed-order fp32 sum -> deterministic.
// ---------------------------------------------------------------------------
__global__ __launch_bounds__(128) void gin_poolhead_kernel(
    const _Float16* __restrict__ x, const int* __restrict__ batch,
    const float* __restrict__ Wh1, const float* __restrict__ bh1,
    const float* __restrict__ Wh2, const float* __restrict__ bh2,
    float* __restrict__ out, int N)
{
    const int gid = blockIdx.x;
    const int t = threadIdx.x;
    __shared__ float gs[D];
    __shared__ float hid[64];

    int lo = 0, hi = N;
    while (lo < hi) { int m = (lo + hi) >> 1; if (batch[m] < gid) lo = m + 1; else hi = m; }
    int s = lo;
    hi = N;
    while (lo < hi) { int m = (lo + hi) >> 1; if (batch[m] < gid + 1) lo = m + 1; else hi = m; }
    int e = lo;
    float a0 = 0.f, a1 = 0.f, a2 = 0.f, a3 = 0.f;
    int i = s;
    for (; i + 4 <= e; i += 4) {
        a0 += (float)x[(long)i * D + t];
        a1 += (float)x[(long)(i + 1) * D + t];
        a2 += (float)x[(long)(i + 2) * D + t];
        a3 += (float)x[(long)(i + 3) * D + t];
    }
    for (; i < e; ++i) a0 += (float)x[(long)i * D + t];
    gs[t] = (a0 + a1) + (a2 + a3);
    __syncthreads();

    if (t < 64) {
        float acc = bh1[t];
        #pragma unroll 4
        for (int k = 0; k < D; ++k) acc = fmaf(gs[k], Wh1[k * 64 + t], acc);
        hid[t] = fmaxf(acc, 0.f);
    }
    __syncthreads();
    if (t < 12) {
        float acc2 = bh2[t];
        #pragma unroll 4
        for (int j = 0; j < 64; ++j) acc2 = fmaf(hid[j], Wh2[j * 12 + t], acc2);
        out[gid * 12 + t] = 1.f / (1.f + __expf(-acc2));
    }
}

// ---------------------------------------------------------------------------
extern "C" void kernel_launch(void* const* d_in, const int* in_sizes, int n_in,
                              void* d_out, int out_size, void* d_ws, size_t ws_size,
                              hipStream_t stream) {
    const float* x    = (const float*)d_in[0];
    const int*   edge = (const int*)d_in[1];
    const int*   batch= (const int*)d_in[2];
    const float* W1   = (const float*)d_in[3];
    const float* b1   = (const float*)d_in[4];
    const float* W2   = (const float*)d_in[5];
    const float* b2   = (const float*)d_in[6];
    const float* bns  = (const float*)d_in[7];
    const float* bnb  = (const float*)d_in[8];
    const float* bnm  = (const float*)d_in[9];
    const float* bnv  = (const float*)d_in[10];
    const float* Wh1  = (const float*)d_in[11];
    const float* bh1  = (const float*)d_in[12];
    const float* Wh2  = (const float*)d_in[13];
    const float* bh2  = (const float*)d_in[14];
    float* outp = (float*)d_out;

    const int* esrc = edge;
    const int* edst = edge + N_EDGES;

    char* ws = (char*)d_ws;
    size_t off = 0;
    auto alloc = [&](size_t bytes) -> void* {
        void* p = ws + off;
        off += (bytes + 255) & ~(size_t)255;
        return p;
    };
    _Float16* x_h   = (_Float16*)alloc((size_t)N_NODES * D * 2);
    _Float16* bufA  = (_Float16*)alloc((size_t)N_NODES * D * 2);
    _Float16* bufB  = (_Float16*)alloc((size_t)N_NODES * D * 2);
    _Float16* Wt1   = (_Float16*)alloc((size_t)3 * D * D * 2);
    _Float16* Wt2   = (_Float16*)alloc((size_t)3 * D * D * 2);
    int*   slots   = (int*)alloc(((size_t)N_NODES * CAP + 64) * 4);  // +pad
    int*   cnt     = (int*)alloc((size_t)N_NODES * 4);
    if (off > ws_size) return;

    hipMemsetAsync(cnt, 0, (size_t)N_NODES * 4, stream);

    gin_prep_kernel<<<PREP_E_BLOCKS + PREP_X_BLOCKS + PREP_W_BLOCKS, 256, 0, stream>>>(
        x, x_h, esrc, edst, cnt, slots, W1, W2, Wt1, Wt2);

    const int GLAYER = (N_NODES + 31) / 32;   // 1563 blocks, 32 nodes each

    // ping-pong: layer reads one buffer, writes the other
    const _Float16* lin[3]  = {x_h,  bufA, bufB};
    _Float16*       lout[3] = {bufA, bufB, bufA};
    for (int l = 0; l < 3; ++l) {
        gin_layer_kernel<<<GLAYER, 256, 0, stream>>>(
            lin[l], cnt, slots,
            Wt1 + (size_t)l * D * D, b1 + l * D,
            Wt2 + (size_t)l * D * D, b2 + l * D,
            bns + l * D, bnb + l * D, bnm + l * D, bnv + l * D,
            lout[l], N_NODES);
    }

    gin_poolhead_kernel<<<N_GRAPHS, 128, 0, stream>>>(bufA, batch, Wh1, bh1, Wh2, bh2, outp, N_NODES);
}

// Round 15
// 270.543 us; speedup vs baseline: 1.0344x; 1.0344x over previous
//
#include <hip/hip_runtime.h>
#include <hip/hip_bf16.h>
#include <hip/hip_fp16.h>

#define N_NODES 50000
#define N_EDGES 640000
#define N_GRAPHS 500
#define D 128
#define CAP 64   // neighbor slots per node; P(Poisson(12.8) > 64) ~ 1e-30

#define PREP_X_BLOCKS (N_NODES * D / 8 / 256) // 3125 (exact)
#define PREP_E_BLOCKS (N_EDGES / 256)         // 2500 (exact), 1 edge/thread
#define PREP_W_BLOCKS (6 * D * D / 256)       // 384 (exact)

typedef _Float16 h8_t __attribute__((ext_vector_type(8)));   // 8 fp16 = 4 VGPRs
typedef __attribute__((ext_vector_type(4))) float f4_t;

// ---------------------------------------------------------------------------
// prep: (a) binned-CSR fill (1 edge/thread; measured at the chip-wide
//       returning-atomic rate ~6.3 ops/cyc -> ~42us, algorithmic wall),
//       (b) x fp32->fp16, (c) W (L,K,N) fp32 -> fp16 transposed (L,N,K).
// ---------------------------------------------------------------------------
__global__ __launch_bounds__(256) void gin_prep_kernel(
    const float* __restrict__ x, _Float16* __restrict__ xh,
    const int* __restrict__ src, const int* __restrict__ dst,
    int* __restrict__ cnt, int* __restrict__ slots,
    const float* __restrict__ W1, const float* __restrict__ W2,
    _Float16* __restrict__ Wt1, _Float16* __restrict__ Wt2)
{
    const int b = blockIdx.x, t = threadIdx.x;
    if (b < PREP_E_BLOCKS) {
        int e = b * 256 + t;                       // one edge per thread
        int s = src[e];
        int d = dst[e];
        int sl = atomicAdd(&cnt[d], 1);
        if (sl < CAP) slots[(d << 6) + sl] = s;
    } else if (b < PREP_E_BLOCKS + PREP_X_BLOCKS) {
        int i = (b - PREP_E_BLOCKS) * 256 + t;     // h8-unit index
        const float4* p = (const float4*)x;
        float4 v0 = p[2 * i], v1 = p[2 * i + 1];
        h8_t o;
        o[0] = (_Float16)v0.x; o[1] = (_Float16)v0.y;
        o[2] = (_Float16)v0.z; o[3] = (_Float16)v0.w;
        o[4] = (_Float16)v1.x; o[5] = (_Float16)v1.y;
        o[6] = (_Float16)v1.z; o[7] = (_Float16)v1.w;
        ((h8_t*)xh)[i] = o;
    } else {
        int idx = (b - PREP_E_BLOCKS - PREP_X_BLOCKS) * 256 + t;
        int m = idx >> 14;
        int r = idx & 16383;
        int n = r >> 7, k = r & 127;
        const float* srcw = (m < 3) ? (W1 + ((long)m << 14)) : (W2 + ((long)(m - 3) << 14));
        _Float16* dstw = (m < 3) ? (Wt1 + ((long)m << 14)) : (Wt2 + ((long)(m - 3) << 14));
        dstw[(n << 7) | k] = (_Float16)srcw[(k << 7) | n];   // Wt[n][k] = W[k][n]
    }
}

// ---------------------------------------------------------------------------
// FUSED LAYER (r12 best-known, reverted after r13 spill / r14 neutral):
// out = relu(BN(relu((x_self + sum_n x) @ W1 + b1) @ W2 + b2))
// Block = 512 thr (8 waves) owns 32 nodes; grid 1563.
//  phase G: wave-per-node, 4 passes; binned slots (uniform base -> s_loads);
//   single clamped 16-window -> ONE vmcnt drain for ~85% of nodes; residual
//   loop for deg>16. TWO independent f64 accumulator pairs. All sums EXACT
//   (fp16 multiples of 2^-24, |v|<2^6, deg<2^6) -> bit-identical for ANY
//   slot order (atomics vary per call).
//   Measured wall: ~1.85 TB/s HBM on random 256B rows across 8 structural
//   variants (r7-r14) — memory-system bound, not issue/ILP/occupancy bound.
//  stage 1: a_s @ W1 (MFMA), h=relu(+b1) back into a_s.
//  stage 2: out = relu(BN(a_s @ W2 + b2)) -> global.
// in/out must differ (caller ping-pongs).
// ---------------------------------------------------------------------------
constexpr int ASTR = 136;   // fp16 elems/row in LDS: +8 pad

__device__ __forceinline__ float2 unpack_h2(unsigned v) {
    __half2 h = __builtin_bit_cast(__half2, v);
    return __half22float2(h);
}

__global__ __launch_bounds__(512, 4) void gin_layer_kernel(
    const _Float16* __restrict__ x,
    const int* __restrict__ cnt, const int* __restrict__ slots,
    const _Float16* __restrict__ Wt1, const float* __restrict__ b1,
    const _Float16* __restrict__ Wt2, const float* __restrict__ b2,
    const float* __restrict__ bn_scale, const float* __restrict__ bn_bias,
    const float* __restrict__ bn_mean, const float* __restrict__ bn_var,
    _Float16* __restrict__ out, int N)
{
    __shared__ __align__(16) _Float16 a_s[32 * ASTR];
    __shared__ float ep_a[D], ep_b[D], b1_s[D];

    const int tid = threadIdx.x;
    if (tid < D) {
        float s = bn_scale[tid] * rsqrtf(bn_var[tid] + 1e-5f);
        ep_a[tid] = s;
        ep_b[tid] = (b2[tid] - bn_mean[tid]) * s + bn_bias[tid];
        b1_s[tid] = b1[tid];
    }

    const int row0 = blockIdx.x * 32;
    const int lane = tid & 63;
    const int wave_u = __builtin_amdgcn_readfirstlane(tid >> 6);   // 0..7, SGPR
    const unsigned* __restrict__ xw = (const unsigned*)x;          // dword = 2 fp16

    // ---- phase G: wave-per-node, single-drain clamped gather ----
    #pragma unroll 1
    for (int pass = 0; pass < 4; ++pass) {
        const int nl = pass * 8 + wave_u;          // 0..31, uniform
        const int node = row0 + nl;
        const bool live = (node < N);
        const int cnt_n = live ? __builtin_amdgcn_readfirstlane(cnt[node]) : 0;
        const int* cp = slots + ((long)node << 6); // uniform base -> s_loads

        double a0 = 0.0, a1 = 0.0, c0 = 0.0, c1 = 0.0;
        if (live) {
            float2 f = unpack_h2(xw[(long)node * 64 + lane]);      // self
            a0 = (double)f.x; a1 = (double)f.y;

            // fixed 16-window: clamped indices for i>=cnt, masked adds
            int idx[16];
            #pragma unroll
            for (int i = 0; i < 16; ++i) idx[i] = cp[i];           // s_loads
            unsigned v[16];
            #pragma unroll
            for (int i = 0; i < 16; ++i) {
                int j = (i < cnt_n) ? idx[i] : 0;                  // scalar select
                v[i] = xw[(long)j * 64 + lane];                    // coalesced 256B
            }
            #pragma unroll
            for (int i = 0; i < 16; i += 2) {                      // 2-way f64 ILP
                unsigned m0 = (i < cnt_n) ? v[i] : 0u;
                unsigned m1 = (i + 1 < cnt_n) ? v[i + 1] : 0u;
                float2 g0 = unpack_h2(m0);
                float2 g1 = unpack_h2(m1);
                a0 += (double)g0.x; a1 += (double)g0.y;
                c0 += (double)g1.x; c1 += (double)g1.y;
            }
            // residual (deg > 16, ~15% of nodes)
            #pragma unroll 1
            for (int k = 16; k < cnt_n; k += 8) {
                unsigned vv[8];
                #pragma unroll
                for (int i = 0; i < 8; ++i) {
                    int kk = k + i;
                    int j = (kk < cnt_n) ? cp[kk] : 0;
                    vv[i] = xw[(long)j * 64 + lane];
                }
                #pragma unroll
                for (int i = 0; i < 8; i += 2) {
                    unsigned m0 = (k + i < cnt_n) ? vv[i] : 0u;
                    unsigned m1 = (k + i + 1 < cnt_n) ? vv[i + 1] : 0u;
                    float2 g0 = unpack_h2(m0);
                    float2 g1 = unpack_h2(m1);
                    a0 += (double)g0.x; a1 += (double)g0.y;
                    c0 += (double)g1.x; c1 += (double)g1.y;
                }
            }
        }
        // merge (exact: every partial sum representable)
        _Float16 h0 = (_Float16)(float)(a0 + c0);
        _Float16 h1 = (_Float16)(float)(a1 + c1);
        unsigned pk = (unsigned)__builtin_bit_cast(unsigned short, h0) |
                      ((unsigned)__builtin_bit_cast(unsigned short, h1) << 16);
        *(unsigned*)(a_s + nl * ASTR + lane * 2) = pk;             // conflict-free
    }
    __syncthreads();

    // ---- stage 1: a_s @ W1 ----  (wave w -> col tile [16w,16w+16), rows 0..31)
    const int m16 = lane & 15;
    const int kq  = lane >> 4;
    const int coln = wave_u * 16 + m16;

    f4_t a1m[2] = {(f4_t){0.f, 0.f, 0.f, 0.f}, (f4_t){0.f, 0.f, 0.f, 0.f}};
    #pragma unroll
    for (int kc = 0; kc < 4; ++kc) {
        const int k0 = kc * 32 + kq * 8;
        h8_t af0 = *(const h8_t*)(a_s + m16 * ASTR + k0);
        h8_t af1 = *(const h8_t*)(a_s + (16 + m16) * ASTR + k0);
        h8_t bf  = *(const h8_t*)(Wt1 + (long)coln * D + k0);
        a1m[0] = __builtin_amdgcn_mfma_f32_16x16x32_f16(af0, bf, a1m[0], 0, 0, 0);
        a1m[1] = __builtin_amdgcn_mfma_f32_16x16x32_f16(af1, bf, a1m[1], 0, 0, 0);
    }
    __syncthreads();   // all a_s reads done -> safe to overwrite

    // h = relu(a1m + b1) back into a_s  (C/D: col=m16, row=kq*4+g)
    {
        const float bb = b1_s[coln];
        #pragma unroll
        for (int r = 0; r < 2; ++r)
            #pragma unroll
            for (int g = 0; g < 4; ++g) {
                float vv = fmaxf(a1m[r][g] + bb, 0.f);
                a_s[(r * 16 + kq * 4 + g) * ASTR + coln] = (_Float16)vv;
            }
    }
    __syncthreads();

    // ---- stage 2: out = relu(BN(a_s @ W2 + b2)) ----
    f4_t a2m[2] = {(f4_t){0.f, 0.f, 0.f, 0.f}, (f4_t){0.f, 0.f, 0.f, 0.f}};
    #pragma unroll
    for (int kc = 0; kc < 4; ++kc) {
        const int k0 = kc * 32 + kq * 8;
        h8_t af0 = *(const h8_t*)(a_s + m16 * ASTR + k0);
        h8_t af1 = *(const h8_t*)(a_s + (16 + m16) * ASTR + k0);
        h8_t bf  = *(const h8_t*)(Wt2 + (long)coln * D + k0);
        a2m[0] = __builtin_amdgcn_mfma_f32_16x16x32_f16(af0, bf, a2m[0], 0, 0, 0);
        a2m[1] = __builtin_amdgcn_mfma_f32_16x16x32_f16(af1, bf, a2m[1], 0, 0, 0);
    }
    {
        const float ea = ep_a[coln], eb = ep_b[coln];
        #pragma unroll
        for (int r = 0; r < 2; ++r) {
            const int rb = row0 + r * 16 + kq * 4;
            #pragma unroll
            for (int g = 0; g < 4; ++g) {
                const int grow = rb + g;
                if (grow < N) {
                    float vv = fmaxf(fmaf(a2m[r][g], ea, eb), 0.f);
                    out[(long)grow * D + coln] = (_Float16)vv;
                }
            }
        }
    }
}

// ---------------------------------------------------------------------------
// fused pool+head: one block (128 thr) per graph. batch sorted -> binary
// search; fixed-order fp32 sum -> deterministic.
// ---------------------------------------------------------------------------
__global__ __launch_bounds__(128) void gin_poolhead_kernel(
    const _Float16* __restrict__ x, const int* __restrict__ batch,
    const float* __restrict__ Wh1, const float* __restrict__ bh1,
    const float* __restrict__ Wh2, const float* __restrict__ bh2,
    float* __restrict__ out, int N)
{
    const int gid = blockIdx.x;
    const int t = threadIdx.x;
    __shared__ float gs[D];
    __shared__ float hid[64];

    int lo = 0, hi = N;
    while (lo < hi) { int m = (lo + hi) >> 1; if (batch[m] < gid) lo = m + 1; else hi = m; }
    int s = lo;
    hi = N;
    while (lo < hi) { int m = (lo + hi) >> 1; if (batch[m] < gid + 1) lo = m + 1; else hi = m; }
    int e = lo;
    float a0 = 0.f, a1 = 0.f, a2 = 0.f, a3 = 0.f;
    int i = s;
    for (; i + 4 <= e; i += 4) {
        a0 += (float)x[(long)i * D + t];
        a1 += (float)x[(long)(i + 1) * D + t];
        a2 += (float)x[(long)(i + 2) * D + t];
        a3 += (float)x[(long)(i + 3) * D + t];
    }
    for (; i < e; ++i) a0 += (float)x[(long)i * D + t];
    gs[t] = (a0 + a1) + (a2 + a3);
    __syncthreads();

    if (t < 64) {
        float acc = bh1[t];
        #pragma unroll 4
        for (int k = 0; k < D; ++k) acc = fmaf(gs[k], Wh1[k * 64 + t], acc);
        hid[t] = fmaxf(acc, 0.f);
    }
    __syncthreads();
    if (t < 12) {
        float acc2 = bh2[t];
        #pragma unroll 4
        for (int j = 0; j < 64; ++j) acc2 = fmaf(hid[j], Wh2[j * 12 + t], acc2);
        out[gid * 12 + t] = 1.f / (1.f + __expf(-acc2));
    }
}

// ---------------------------------------------------------------------------
extern "C" void kernel_launch(void* const* d_in, const int* in_sizes, int n_in,
                              void* d_out, int out_size, void* d_ws, size_t ws_size,
                              hipStream_t stream) {
    const float* x    = (const float*)d_in[0];
    const int*   edge = (const int*)d_in[1];
    const int*   batch= (const int*)d_in[2];
    const float* W1   = (const float*)d_in[3];
    const float* b1   = (const float*)d_in[4];
    const float* W2   = (const float*)d_in[5];
    const float* b2   = (const float*)d_in[6];
    const float* bns  = (const float*)d_in[7];
    const float* bnb  = (const float*)d_in[8];
    const float* bnm  = (const float*)d_in[9];
    const float* bnv  = (const float*)d_in[10];
    const float* Wh1  = (const float*)d_in[11];
    const float* bh1  = (const float*)d_in[12];
    const float* Wh2  = (const float*)d_in[13];
    const float* bh2  = (const float*)d_in[14];
    float* outp = (float*)d_out;

    const int* esrc = edge;
    const int* edst = edge + N_EDGES;

    char* ws = (char*)d_ws;
    size_t off = 0;
    auto alloc = [&](size_t bytes) -> void* {
        void* p = ws + off;
        off += (bytes + 255) & ~(size_t)255;
        return p;
    };
    _Float16* x_h   = (_Float16*)alloc((size_t)N_NODES * D * 2);
    _Float16* bufA  = (_Float16*)alloc((size_t)N_NODES * D * 2);
    _Float16* bufB  = (_Float16*)alloc((size_t)N_NODES * D * 2);
    _Float16* Wt1   = (_Float16*)alloc((size_t)3 * D * D * 2);
    _Float16* Wt2   = (_Float16*)alloc((size_t)3 * D * D * 2);
    int*   slots   = (int*)alloc(((size_t)N_NODES * CAP + 64) * 4);  // +pad for s_load overrun
    int*   cnt     = (int*)alloc((size_t)N_NODES * 4);
    if (off > ws_size) return;

    hipMemsetAsync(cnt, 0, (size_t)N_NODES * 4, stream);

    gin_prep_kernel<<<PREP_E_BLOCKS + PREP_X_BLOCKS + PREP_W_BLOCKS, 256, 0, stream>>>(
        x, x_h, esrc, edst, cnt, slots, W1, W2, Wt1, Wt2);

    const int GLAYER = (N_NODES + 31) / 32;   // 1563 blocks, 32 nodes each

    // ping-pong: layer reads one buffer, writes the other
    const _Float16* lin[3]  = {x_h,  bufA, bufB};
    _Float16*       lout[3] = {bufA, bufB, bufA};
    for (int l = 0; l < 3; ++l) {
        gin_layer_kernel<<<GLAYER, 512, 0, stream>>>(
            lin[l], cnt, slots,
            Wt1 + (size_t)l * D * D, b1 + l * D,
            Wt2 + (size_t)l * D * D, b2 + l * D,
            bns + l * D, bnb + l * D, bnm + l * D, bnv + l * D,
            lout[l], N_NODES);
    }

    gin_poolhead_kernel<<<N_GRAPHS, 128, 0, stream>>>(bufA, batch, Wh1, bh1, Wh2, bh2, outp, N_NODES);
}